// Round 1
// baseline (963.503 us; speedup 1.0000x reference)
//
#include <hip/hip_runtime.h>
#include <math.h>
#include <float.h>

// Problem constants (fixed by reference)
#define B_   8
#define F_   2048
#define N_   10000
#define J_   10
#define R_   20
#define H1_  200
#define H2_  100

// Conv kernel tiling
#define FC_     8              // F chunks (grid.z)  -> 20*8*8 = 1280 blocks = 5/CU
#define FCHUNK  (F_ / FC_)     // 256 f per chunk
#define VN      2              // n's per thread (float2 load)
#define T1      256
#define NPB     (T1 * VN)      // 512 n per block
#define NB      ((N_ + NPB - 1) / NPB)   // 20

// ---------------------------------------------------------------------------
// Kernel 1: partial 1x1 conv  emb[b,j,n] += sum_{f in chunk} x[b,f,n]*w[j,f]
// ---------------------------------------------------------------------------
__global__ __launch_bounds__(T1) void conv_kernel(
    const float* __restrict__ x, const float* __restrict__ w,
    float* __restrict__ emb)
{
    const int tid = threadIdx.x;
    const int nb  = blockIdx.x;
    const int b   = blockIdx.y;
    const int fc  = blockIdx.z;

    const int n0 = nb * NPB + tid * VN;
    if (n0 >= N_) return;                  // N_ even, so n0+1 also in range
    const int fbeg = fc * FCHUNK;

    const float* px = x + ((size_t)b * F_ + fbeg) * N_ + n0;
    const float* pw = w + fbeg;            // pw[j*F_ + f] , f in [0,FCHUNK)

    float ax[J_], ay[J_];
#pragma unroll
    for (int j = 0; j < J_; ++j) { ax[j] = 0.f; ay[j] = 0.f; }

#pragma unroll 4
    for (int f = 0; f < FCHUNK; ++f) {
        const float2 xv = *(const float2*)px;
        px += N_;
#pragma unroll
        for (int j = 0; j < J_; ++j) {
            const float wv = pw[j * F_ + f];     // wave-uniform -> s_load/L1 bcast
            ax[j] = fmaf(wv, xv.x, ax[j]);
            ay[j] = fmaf(wv, xv.y, ay[j]);
        }
    }

    float* pe = emb + (size_t)b * J_ * N_ + n0;
#pragma unroll
    for (int j = 0; j < J_; ++j) {
        atomicAdd(pe + (size_t)j * N_,     ax[j]);
        atomicAdd(pe + (size_t)j * N_ + 1, ay[j]);
    }
}

// ---------------------------------------------------------------------------
// Kernel 2: per (b,j) row -> top-20 desc + bottom-20 desc, +bias, into mm
// ---------------------------------------------------------------------------
#define T2  256
#define LPT 20

__global__ __launch_bounds__(T2) void select_kernel(
    const float* __restrict__ emb, const float* __restrict__ conv_b,
    float* __restrict__ mm)
{
    __shared__ float ls_top[T2 * LPT];   // 20 KB
    __shared__ float ls_bot[T2 * LPT];   // 20 KB
    __shared__ float s_val[8];
    __shared__ int   s_tid[8];
    __shared__ float s_wv;
    __shared__ int   s_wt;

    const int tid = threadIdx.x;
    const int j   = blockIdx.x;
    const int b   = blockIdx.y;

    const float* row = emb + ((size_t)b * J_ + j) * N_;

    // per-thread sorted lists (top: descending, bot: ascending)
    float top[LPT], bot[LPT];
#pragma unroll
    for (int k = 0; k < LPT; ++k) { top[k] = -FLT_MAX; bot[k] = FLT_MAX; }

    for (int n = tid; n < N_; n += T2) {
        const float v = row[n];
        float tv = v;
#pragma unroll
        for (int k = 0; k < LPT; ++k) {
            if (tv > top[k]) { const float o = top[k]; top[k] = tv; tv = o; }
        }
        float bv = v;
#pragma unroll
        for (int k = 0; k < LPT; ++k) {
            if (bv < bot[k]) { const float o = bot[k]; bot[k] = bv; bv = o; }
        }
    }
#pragma unroll
    for (int k = 0; k < LPT; ++k) {
        ls_top[tid * LPT + k] = top[k];
        ls_bot[tid * LPT + k] = bot[k];
    }
    __syncthreads();

    const float bias = conv_b[j];
    float* out = mm + ((size_t)b * J_ + j) * (2 * R_);

    const int lane = tid & 63;
    const int wv_  = tid >> 6;
    int ht = 0, hb = 0;

    for (int r = 0; r < R_; ++r) {
        // ---- argmax round (256-way merge on list heads) ----
        {
            float v = ls_top[tid * LPT + ht];
            int   t = tid;
            for (int off = 32; off; off >>= 1) {
                const float vo = __shfl_down(v, off);
                const int   to = __shfl_down(t, off);
                if (vo > v) { v = vo; t = to; }
            }
            if (lane == 0) { s_val[wv_] = v; s_tid[wv_] = t; }
            __syncthreads();
            if (tid == 0) {
                float bv2 = s_val[0]; int bt = s_tid[0];
                for (int q = 1; q < T2 / 64; ++q)
                    if (s_val[q] > bv2) { bv2 = s_val[q]; bt = s_tid[q]; }
                s_wv = bv2; s_wt = bt;
            }
            __syncthreads();
            if (tid == s_wt) { ht++; out[r] = s_wv + bias; }
            __syncthreads();
        }
        // ---- argmin round ----
        {
            float v = ls_bot[tid * LPT + hb];
            int   t = tid;
            for (int off = 32; off; off >>= 1) {
                const float vo = __shfl_down(v, off);
                const int   to = __shfl_down(t, off);
                if (vo < v) { v = vo; t = to; }
            }
            if (lane == 0) { s_val[wv_] = v; s_tid[wv_] = t; }
            __syncthreads();
            if (tid == 0) {
                float bv2 = s_val[0]; int bt = s_tid[0];
                for (int q = 1; q < T2 / 64; ++q)
                    if (s_val[q] < bv2) { bv2 = s_val[q]; bt = s_tid[q]; }
                s_wv = bv2; s_wt = bt;
            }
            __syncthreads();
            // ascending r-th smallest -> position 39-r (bottom block stored descending)
            if (tid == s_wt) { hb++; out[2 * R_ - 1 - r] = s_wv + bias; }
            __syncthreads();
        }
    }
}

// ---------------------------------------------------------------------------
// Kernel 3: tiny MLP  [8,400] -> sigmoid(400x200) -> sigmoid(200x100) -> 100x2
// ---------------------------------------------------------------------------
__global__ __launch_bounds__(256) void mlp_kernel(
    const float* __restrict__ mm,
    const float* __restrict__ w1, const float* __restrict__ b1,
    const float* __restrict__ w2, const float* __restrict__ b2,
    const float* __restrict__ w3, const float* __restrict__ b3,
    float* __restrict__ out)
{
    __shared__ float h0[2 * R_ * J_];   // 400
    __shared__ float h1[H1_];           // 200
    __shared__ float h2[H2_];           // 100

    const int tid = threadIdx.x;
    const int b   = blockIdx.x;

    for (int i = tid; i < 2 * R_ * J_; i += 256) h0[i] = mm[b * 2 * R_ * J_ + i];
    __syncthreads();

    if (tid < H1_) {
        float acc = b1[tid];
#pragma unroll 4
        for (int i = 0; i < 2 * R_ * J_; ++i)
            acc = fmaf(h0[i], w1[i * H1_ + tid], acc);
        h1[tid] = 1.f / (1.f + expf(-acc));
    }
    __syncthreads();

    if (tid < H2_) {
        float acc = b2[tid];
#pragma unroll 4
        for (int i = 0; i < H1_; ++i)
            acc = fmaf(h1[i], w2[i * H2_ + tid], acc);
        h2[tid] = 1.f / (1.f + expf(-acc));
    }
    __syncthreads();

    if (tid < 2) {
        float acc = b3[tid];
        for (int i = 0; i < H2_; ++i)
            acc = fmaf(h2[i], w3[i * 2 + tid], acc);
        out[b * 2 + tid] = acc;
    }
}

// ---------------------------------------------------------------------------
extern "C" void kernel_launch(void* const* d_in, const int* in_sizes, int n_in,
                              void* d_out, int out_size, void* d_ws, size_t ws_size,
                              hipStream_t stream)
{
    const float* x      = (const float*)d_in[0];
    const float* conv_w = (const float*)d_in[1];
    const float* conv_b = (const float*)d_in[2];
    const float* w1     = (const float*)d_in[3];
    const float* b1     = (const float*)d_in[4];
    const float* w2     = (const float*)d_in[5];
    const float* b2     = (const float*)d_in[6];
    const float* w3     = (const float*)d_in[7];
    const float* b3     = (const float*)d_in[8];

    float* emb = (float*)d_ws;                         // B*J*N floats = 3.2 MB
    float* mm  = emb + (size_t)B_ * J_ * N_;           // B*J*2R = 3200 floats
    float* out = (float*)d_out;

    // emb accumulated via atomics -> must start at zero (ws is poisoned 0xAA)
    hipMemsetAsync(emb, 0, (size_t)B_ * J_ * N_ * sizeof(float), stream);

    conv_kernel<<<dim3(NB, B_, FC_), T1, 0, stream>>>(x, conv_w, emb);
    select_kernel<<<dim3(J_, B_), T2, 0, stream>>>(emb, conv_b, mm);
    mlp_kernel<<<B_, 256, 0, stream>>>(mm, w1, b1, w2, b2, w3, b3, out);
}

// Round 2
// 956.862 us; speedup vs baseline: 1.0069x; 1.0069x over previous
//
#include <hip/hip_runtime.h>
#include <math.h>
#include <float.h>

// Problem constants (fixed by reference)
#define B_   8
#define F_   2048
#define N_   10000
#define J_   10
#define R_   20
#define H1_  200
#define H2_  100

// Conv tiling: 16 F-chunks x 8 batches x 10 n-blocks = 1280 blocks = 5/CU exact.
// Each block: 128 f x 1024 n, float4 loads (16B/lane coalescing sweet spot).
// Partial sums go to 16 separate planes (plain stores, NO atomics) and are
// reduced inside select_kernel (51 MB extra traffic ~= 8 us, vs the measured
// multi-hundred-us cost risk of 6.5M device-scope atomics on non-coherent XCD L2s).
#define FC_     16
#define FCHUNK  (F_ / FC_)     // 128
#define VN      4
#define T1      256
#define NPB     (T1 * VN)      // 1024
#define NB      ((N_ + NPB - 1) / NPB)   // 10
#define PLANE   ((size_t)B_ * J_ * N_)   // 800,000 floats per partial plane

// ---------------------------------------------------------------------------
// Kernel 1: partial 1x1 conv  part[fc][b][j][n] = sum_{f in chunk} x[b,f,n]*w[j,f]
// ---------------------------------------------------------------------------
__global__ __launch_bounds__(T1) void conv_kernel(
    const float* __restrict__ x, const float* __restrict__ w,
    float* __restrict__ part)
{
    const int tid = threadIdx.x;
    const int nb  = blockIdx.x;
    const int b   = blockIdx.y;
    const int fc  = blockIdx.z;

    const int n0 = nb * NPB + tid * VN;
    if (n0 >= N_) return;                  // N_ % 4 == 0, so full float4 in range
    const int fbeg = fc * FCHUNK;

    const float* px = x + ((size_t)b * F_ + fbeg) * N_ + n0;
    const float* pw = w + fbeg;            // pw[j*F_ + f], wave-uniform -> s_load

    float4 acc[J_];
#pragma unroll
    for (int j = 0; j < J_; ++j) acc[j] = make_float4(0.f, 0.f, 0.f, 0.f);

#pragma unroll 2
    for (int f = 0; f < FCHUNK; ++f) {
        const float4 xv = *(const float4*)px;
        px += N_;
#pragma unroll
        for (int j = 0; j < J_; ++j) {
            const float wv = pw[j * F_ + f];
            acc[j].x = fmaf(wv, xv.x, acc[j].x);
            acc[j].y = fmaf(wv, xv.y, acc[j].y);
            acc[j].z = fmaf(wv, xv.z, acc[j].z);
            acc[j].w = fmaf(wv, xv.w, acc[j].w);
        }
    }

    float* pe = part + (size_t)fc * PLANE + ((size_t)b * J_) * N_ + n0;
#pragma unroll
    for (int j = 0; j < J_; ++j) {
        *(float4*)(pe + (size_t)j * N_) = acc[j];
    }
}

// ---------------------------------------------------------------------------
// Kernel 2: per (b,j) row: sum the 16 partial planes, then top-20 desc +
// bottom-20 desc (+bias post-selection; uniform shift preserves order) -> mm
// ---------------------------------------------------------------------------
#define T2  256
#define LPT 20

__global__ __launch_bounds__(T2) void select_kernel(
    const float* __restrict__ part, const float* __restrict__ conv_b,
    float* __restrict__ mm)
{
    __shared__ float ls_top[T2 * LPT];   // 20 KB
    __shared__ float ls_bot[T2 * LPT];   // 20 KB
    __shared__ float s_val[8];
    __shared__ int   s_tid[8];
    __shared__ float s_wv;
    __shared__ int   s_wt;

    const int tid = threadIdx.x;
    const int j   = blockIdx.x;
    const int b   = blockIdx.y;

    const float* row = part + ((size_t)b * J_ + j) * N_;   // plane 0

    // per-thread sorted lists (top: descending, bot: ascending)
    float top[LPT], bot[LPT];
#pragma unroll
    for (int k = 0; k < LPT; ++k) { top[k] = -FLT_MAX; bot[k] = FLT_MAX; }

    for (int n = tid; n < N_; n += T2) {
        float v = 0.f;
#pragma unroll
        for (int fc = 0; fc < FC_; ++fc) v += row[(size_t)fc * PLANE + n];

        float tv = v;
#pragma unroll
        for (int k = 0; k < LPT; ++k) {
            if (tv > top[k]) { const float o = top[k]; top[k] = tv; tv = o; }
        }
        float bv = v;
#pragma unroll
        for (int k = 0; k < LPT; ++k) {
            if (bv < bot[k]) { const float o = bot[k]; bot[k] = bv; bv = o; }
        }
    }
#pragma unroll
    for (int k = 0; k < LPT; ++k) {
        ls_top[tid * LPT + k] = top[k];
        ls_bot[tid * LPT + k] = bot[k];
    }
    __syncthreads();

    const float bias = conv_b[j];
    float* out = mm + ((size_t)b * J_ + j) * (2 * R_);

    const int lane = tid & 63;
    const int wv_  = tid >> 6;
    int ht = 0, hb = 0;

    for (int r = 0; r < R_; ++r) {
        // ---- argmax round (256-way merge on list heads) ----
        {
            float v = ls_top[tid * LPT + ht];
            int   t = tid;
            for (int off = 32; off; off >>= 1) {
                const float vo = __shfl_down(v, off);
                const int   to = __shfl_down(t, off);
                if (vo > v) { v = vo; t = to; }
            }
            if (lane == 0) { s_val[wv_] = v; s_tid[wv_] = t; }
            __syncthreads();
            if (tid == 0) {
                float bv2 = s_val[0]; int bt = s_tid[0];
                for (int q = 1; q < T2 / 64; ++q)
                    if (s_val[q] > bv2) { bv2 = s_val[q]; bt = s_tid[q]; }
                s_wv = bv2; s_wt = bt;
            }
            __syncthreads();
            if (tid == s_wt) { ht++; out[r] = s_wv + bias; }
            __syncthreads();
        }
        // ---- argmin round ----
        {
            float v = ls_bot[tid * LPT + hb];
            int   t = tid;
            for (int off = 32; off; off >>= 1) {
                const float vo = __shfl_down(v, off);
                const int   to = __shfl_down(t, off);
                if (vo < v) { v = vo; t = to; }
            }
            if (lane == 0) { s_val[wv_] = v; s_tid[wv_] = t; }
            __syncthreads();
            if (tid == 0) {
                float bv2 = s_val[0]; int bt = s_tid[0];
                for (int q = 1; q < T2 / 64; ++q)
                    if (s_val[q] < bv2) { bv2 = s_val[q]; bt = s_tid[q]; }
                s_wv = bv2; s_wt = bt;
            }
            __syncthreads();
            // ascending r-th smallest -> position 39-r (bottom block stored descending)
            if (tid == s_wt) { hb++; out[2 * R_ - 1 - r] = s_wv + bias; }
            __syncthreads();
        }
    }
}

// ---------------------------------------------------------------------------
// Kernel 3: tiny MLP  [8,400] -> sigmoid(400x200) -> sigmoid(200x100) -> 100x2
// ---------------------------------------------------------------------------
__global__ __launch_bounds__(256) void mlp_kernel(
    const float* __restrict__ mm,
    const float* __restrict__ w1, const float* __restrict__ b1,
    const float* __restrict__ w2, const float* __restrict__ b2,
    const float* __restrict__ w3, const float* __restrict__ b3,
    float* __restrict__ out)
{
    __shared__ float h0[2 * R_ * J_];   // 400
    __shared__ float h1[H1_];           // 200
    __shared__ float h2[H2_];           // 100

    const int tid = threadIdx.x;
    const int b   = blockIdx.x;

    for (int i = tid; i < 2 * R_ * J_; i += 256) h0[i] = mm[b * 2 * R_ * J_ + i];
    __syncthreads();

    if (tid < H1_) {
        float acc = b1[tid];
#pragma unroll 4
        for (int i = 0; i < 2 * R_ * J_; ++i)
            acc = fmaf(h0[i], w1[i * H1_ + tid], acc);
        h1[tid] = 1.f / (1.f + expf(-acc));
    }
    __syncthreads();

    if (tid < H2_) {
        float acc = b2[tid];
#pragma unroll 4
        for (int i = 0; i < H1_; ++i)
            acc = fmaf(h1[i], w2[i * H2_ + tid], acc);
        h2[tid] = 1.f / (1.f + expf(-acc));
    }
    __syncthreads();

    if (tid < 2) {
        float acc = b3[tid];
        for (int i = 0; i < H2_; ++i)
            acc = fmaf(h2[i], w3[i * 2 + tid], acc);
        out[b * 2 + tid] = acc;
    }
}

// ---------------------------------------------------------------------------
extern "C" void kernel_launch(void* const* d_in, const int* in_sizes, int n_in,
                              void* d_out, int out_size, void* d_ws, size_t ws_size,
                              hipStream_t stream)
{
    const float* x      = (const float*)d_in[0];
    const float* conv_w = (const float*)d_in[1];
    const float* conv_b = (const float*)d_in[2];
    const float* w1     = (const float*)d_in[3];
    const float* b1     = (const float*)d_in[4];
    const float* w2     = (const float*)d_in[5];
    const float* b2     = (const float*)d_in[6];
    const float* w3     = (const float*)d_in[7];
    const float* b3     = (const float*)d_in[8];

    float* part = (float*)d_ws;                        // 16 planes x 3.2 MB = 51.2 MB
    float* mm   = part + (size_t)FC_ * PLANE;          // B*J*2R = 3200 floats
    float* out  = (float*)d_out;

    conv_kernel<<<dim3(NB, B_, FC_), T1, 0, stream>>>(x, conv_w, part);
    select_kernel<<<dim3(J_, B_), T2, 0, stream>>>(part, conv_b, mm);
    mlp_kernel<<<B_, 256, 0, stream>>>(mm, w1, b1, w2, b2, w3, b3, out);
}